// Round 12
// baseline (56.726 us; speedup 1.0000x reference)
//
#include <hip/hip_runtime.h>
#include <hip/hip_bf16.h>

#define H_IMG 720
#define W_IMG 1280
#define NPIX (H_IMG * W_IMG)

typedef __attribute__((ext_vector_type(4))) float f32x4;
typedef __attribute__((ext_vector_type(8))) short short8;
typedef __attribute__((ext_vector_type(4))) short short4v;
typedef __attribute__((ext_vector_type(4))) uint u32x4;
typedef _Float16 h8 __attribute__((ext_vector_type(8)));

// ---- workspace layout (bytes) ----
// wpack: 14 f16 A-frags * 64 lanes * 16B
#define WPACK_BYTES (14 * 64 * 16)
#define GP0_OFF WPACK_BYTES                  // 14336 (16-aligned)
#define GP0_N (16 * 16 * 8 * 8)              // f16 elems, [y][x][z][c]
#define GP1_OFF (GP0_OFF + GP0_N * 2)        // 47104
#define GP1_N (12 * 12 * 8 * 8)
#define GP2_OFF (GP1_OFF + GP1_N * 2)        // 65536
#define GP2_N (8 * 8 * 4 * 8)

#define XSTR 36  // ushorts per staging row: 32 payload + 4 pad

// 2*log2(e): folded into w1/w2 at prep so MFMA emits exp2-ready values.
#define KSCALE 2.885390081777927f

__device__ __forceinline__ uint pkh(float a, float b) {
  // v_cvt_pkrtz_f16_f32: 2 f32 -> packed f16x2, one instruction
  auto t = __builtin_amdgcn_cvt_pkrtz(a, b);  // __fp16 ext_vector(2)
  return __builtin_bit_cast(uint, t);
}

// tanh on 4 pre-scaled values u = 2*log2(e)*x, with ONE rcp shared across 4:
// tanh = 1 - 2/(1+2^u). d_i = 2^{u_i}+1; r = 1/(d0 d1 d2 d3);
// 1/d0 = r*(d2 d3)*d1 etc. Clamp |u|<=30 -> D <= 1.3e36, no overflow;
// tanh(u=30 -> x=10.4) off by 2e-9. Saves 3 of 4 rcp (trans-pipe).
__device__ __forceinline__ uint2 tanh4_pk(f32x4 u) {
  float u0 = fminf(fmaxf(u[0], -30.f), 30.f);
  float u1 = fminf(fmaxf(u[1], -30.f), 30.f);
  float u2 = fminf(fmaxf(u[2], -30.f), 30.f);
  float u3 = fminf(fmaxf(u[3], -30.f), 30.f);
  float d0 = __builtin_amdgcn_exp2f(u0) + 1.f;
  float d1 = __builtin_amdgcn_exp2f(u1) + 1.f;
  float d2 = __builtin_amdgcn_exp2f(u2) + 1.f;
  float d3 = __builtin_amdgcn_exp2f(u3) + 1.f;
  float p01 = d0 * d1, p23 = d2 * d3;
  float r = __builtin_amdgcn_rcpf(p01 * p23);
  float m2r = -2.f * r;
  float m2q01 = m2r * p23;  // = -2/(d0*d1)
  float m2q23 = m2r * p01;  // = -2/(d2*d3)
  float t0 = fmaf(m2q01, d1, 1.f);
  float t1 = fmaf(m2q01, d0, 1.f);
  float t2 = fmaf(m2q23, d3, 1.f);
  float t3 = fmaf(m2q23, d2, 1.f);
  return make_uint2(pkh(t0, t1), pkh(t2, t3));
}

// ================= prep kernel =================
__global__ __launch_bounds__(256) void prep_kernel(
    const float* __restrict__ g0, const float* __restrict__ g1, const float* __restrict__ g2,
    const float* __restrict__ w1, const float* __restrict__ w2, const float* __restrict__ w3,
    const int* __restrict__ cam, void* __restrict__ ws) {
  ushort* wpack = (ushort*)ws;
  ushort* gp0 = (ushort*)((char*)ws + GP0_OFF);
  ushort* gp1 = (ushort*)((char*)ws + GP1_OFF);
  ushort* gp2 = (ushort*)((char*)ws + GP2_OFF);
  const int ci = cam[0];
  const int tid = blockIdx.x * 256 + threadIdx.x;
  const int nth = gridDim.x * 256;

  // grids -> [y][x][z][c] f16, selected view only
  for (int e = tid; e < GP0_N; e += nth) {
    int c = e & 7; int t = e >> 3; int z = t & 7; t >>= 3; int x = t & 15; int y = t >> 4;
    _Float16 hv = (_Float16)g0[ci * GP0_N + ((c * 8 + z) * 16 + y) * 16 + x];
    gp0[e] = __builtin_bit_cast(ushort, hv);
  }
  for (int e = tid; e < GP1_N; e += nth) {
    int c = e & 7; int t = e >> 3; int z = t & 7; t >>= 3; int x = t % 12; int y = t / 12;
    _Float16 hv = (_Float16)g1[ci * GP1_N + ((c * 8 + z) * 12 + y) * 12 + x];
    gp1[e] = __builtin_bit_cast(ushort, hv);
  }
  for (int e = tid; e < GP2_N; e += nth) {
    int c = e & 7; int t = e >> 3; int z = t & 3; t >>= 2; int x = t & 7; int y = t >> 3;
    _Float16 hv = (_Float16)g2[ci * GP2_N + ((c * 4 + z) * 8 + y) * 8 + x];
    gp2[e] = __builtin_bit_cast(ushort, hv);
  }

  // weights -> per-lane f16 A-fragments (A = W^T).
  // frag f: 0..3 = L1 (mt), 4..11 = L2 (4+ks*4+mt), 12..13 = L3 (ks).
  // w1/w2 are scaled by KSCALE (tanh exp2 pre-scale); w3 raw.
  for (int fl = tid; fl < 14 * 64; fl += nth) {
    int f = fl >> 6, lane = fl & 63;
    int g = lane >> 4, r = lane & 15;
    ushort* dh = wpack + fl * 8;
#pragma unroll
    for (int j = 0; j < 8; ++j) {
      float v = 0.f;
      if (f < 4) {
        int k = 8 * g + j, n = r + 16 * f;
        if (k < 24) v = w1[k * 64 + n] * KSCALE;
      } else if (f < 12) {
        int q = f - 4, ks = q >> 2, mt = q & 3;
        v = w2[(8 * g + j + 32 * ks) * 64 + (r + 16 * mt)] * KSCALE;
      } else {
        int ks = f - 12;
        if (r < 12) v = w3[(8 * g + j + 32 * ks) * 12 + r];
      }
      _Float16 hv = (_Float16)v;
      dh[j] = __builtin_bit_cast(ushort, hv);
    }
  }
}

// ================= slicing (packed f16) =================
template <int WG, int HG, int LG>
__device__ __forceinline__ h8 slice_h8(const h8* __restrict__ gp,
                                       int row, int col, float gray) {
  float x = (float)col * ((float)(WG - 1) / (float)(W_IMG - 1));
  float y = (float)row * ((float)(HG - 1) / (float)(H_IMG - 1));
  float z = gray * (float)(LG - 1);
  int x0 = (int)x, y0 = (int)y, z0 = (int)z;
  int x1 = min(x0 + 1, WG - 1), y1 = min(y0 + 1, HG - 1), z1 = min(z0 + 1, LG - 1);
  _Float16 wx = (_Float16)(x - (float)x0);
  _Float16 wy = (_Float16)(y - (float)y0);
  _Float16 wz = (_Float16)(z - (float)z0);
  h8 wx8 = {wx, wx, wx, wx, wx, wx, wx, wx};
  h8 wy8 = {wy, wy, wy, wy, wy, wy, wy, wy};
  h8 wz8 = {wz, wz, wz, wz, wz, wz, wz, wz};

  const h8* p00 = gp + (y0 * WG + x0) * LG;
  const h8* p01 = gp + (y0 * WG + x1) * LG;
  const h8* p10 = gp + (y1 * WG + x0) * LG;
  const h8* p11 = gp + (y1 * WG + x1) * LG;

  h8 a00 = p00[z0], a01 = p01[z0], a10 = p10[z0], a11 = p11[z0];
  h8 b00 = p00[z1], b01 = p01[z1], b10 = p10[z1], b11 = p11[z1];

  h8 xa = a00 + wx8 * (a01 - a00);
  h8 xb = a10 + wx8 * (a11 - a10);
  h8 ya = xa + wy8 * (xb - xa);
  h8 xc = b00 + wx8 * (b01 - b00);
  h8 xd = b10 + wx8 * (b11 - b10);
  h8 yb = xc + wy8 * (xd - xc);
  return ya + wz8 * (yb - ya);
}

// ================= main kernel =================
// 1-wave workgroups; wave-private LDS staging (X -> H1a/H1b -> H2a/H2b reuse
// one 64x36-ushort region); no barriers. f16 datapath end-to-end.
// tanh: weights pre-scaled by 2*log2(e) (no per-value mul), 4-way shared rcp.
// launch_bounds(64,4): VGPR budget 128; allocator lands ~56-64, no spill (r9/r11).
__global__ __launch_bounds__(64, 4) void msnbat_kernel(
    const float* __restrict__ rgb, const void* __restrict__ ws, float* __restrict__ out) {
  __shared__ ushort W[64 * XSTR];  // 4608 B/block
  uint* Wu = (uint*)W;

  const h8* wp = (const h8*)ws;  // A-frag f, lane l -> wp[f*64+l]
  const h8* gp0 = (const h8*)((const char*)ws + GP0_OFF);
  const h8* gp1 = (const h8*)((const char*)ws + GP1_OFF);
  const h8* gp2 = (const h8*)((const char*)ws + GP2_OFF);

  const int lane = threadIdx.x;
  const int g = lane >> 4, r = lane & 15;
  const int pixbase = blockIdx.x * 64;
  const int p = pixbase + lane;
  const int row = p / W_IMG;
  const int col = p - row * W_IMG;

  const float rr = rgb[p * 3 + 0], gg = rgb[p * 3 + 1], bb = rgb[p * 3 + 2];
  const float gray = fminf(fmaxf(rr * 0.299f + gg * 0.587f + bb * 0.114f, 0.f), 1.f);

  // ---- slice 24 features (lane = its own pixel), f16 vectors ----
  h8 f0 = slice_h8<16, 16, 8>(gp0, row, col, gray);
  h8 f1 = slice_h8<12, 12, 8>(gp1, row, col, gray);
  h8 f2 = slice_h8<8, 8, 4>(gp2, row, col, gray);

  // ---- stage X: row = pixel(lane), cols 0..23 f16 feats (24..31 unwritten) ----
  {
    const int ub = lane * 18;  // uint base of this row
    u32x4 u0 = __builtin_bit_cast(u32x4, f0);
    u32x4 u1 = __builtin_bit_cast(u32x4, f1);
    u32x4 u2 = __builtin_bit_cast(u32x4, f2);
    *(uint2*)&Wu[ub + 0] = make_uint2(u0[0], u0[1]);
    *(uint2*)&Wu[ub + 2] = make_uint2(u0[2], u0[3]);
    *(uint2*)&Wu[ub + 4] = make_uint2(u1[0], u1[1]);
    *(uint2*)&Wu[ub + 6] = make_uint2(u1[2], u1[3]);
    *(uint2*)&Wu[ub + 8] = make_uint2(u2[0], u2[1]);
    *(uint2*)&Wu[ub + 10] = make_uint2(u2[2], u2[3]);
  }

  const h8 zero8 = (h8){0, 0, 0, 0, 0, 0, 0, 0};

  // ---- B1 frags: lane(g,r) reads X[pixel r+16nt][feat 8g+j]; g==3 = K-pad -> 0 ----
  h8 B1[4];
#pragma unroll
  for (int nt = 0; nt < 4; ++nt) {
    short4v lo = *(short4v*)&W[(r + 16 * nt) * XSTR + 8 * g];
    short4v hi = *(short4v*)&W[(r + 16 * nt) * XSTR + 8 * g + 4];
    short8 s = __builtin_shufflevector(lo, hi, 0, 1, 2, 3, 4, 5, 6, 7);
    B1[nt] = (g < 3) ? __builtin_bit_cast(h8, s) : zero8;
  }

  // ---- L1 (24->64) in mt-halves; stage tanh(H1) halves; build B2 frags ----
  h8 B2[2][4];
#pragma unroll
  for (int half = 0; half < 2; ++half) {
#pragma unroll
    for (int mtl = 0; mtl < 2; ++mtl) {
      const int mt = 2 * half + mtl;
      h8 A = wp[mt * 64 + lane];
      f32x4 a[4];
#pragma unroll
      for (int nt = 0; nt < 4; ++nt) a[nt] = (f32x4){0.f, 0.f, 0.f, 0.f};
#pragma unroll
      for (int nt = 0; nt < 4; ++nt)
        a[nt] = __builtin_amdgcn_mfma_f32_16x16x32_f16(A, B1[nt], a[nt], 0, 0, 0);
#pragma unroll
      for (int nt = 0; nt < 4; ++nt) {
        uint2 v = tanh4_pk(a[nt]);
        *(uint2*)&Wu[(16 * nt + r) * 18 + 8 * mtl + 2 * g] = v;
      }
    }
#pragma unroll
    for (int nt = 0; nt < 4; ++nt) {
      short4v lo = *(short4v*)&W[(16 * nt + r) * XSTR + 8 * g];
      short4v hi = *(short4v*)&W[(16 * nt + r) * XSTR + 8 * g + 4];
      short8 s = __builtin_shufflevector(lo, hi, 0, 1, 2, 3, 4, 5, 6, 7);
      B2[half][nt] = __builtin_bit_cast(h8, s);
    }
  }

  // ---- L2 (64->64) in mt-halves; stage tanh(H2) halves; build B3 frags ----
  h8 B3[2][4];
#pragma unroll
  for (int half = 0; half < 2; ++half) {
#pragma unroll
    for (int mtl = 0; mtl < 2; ++mtl) {
      const int mt = 2 * half + mtl;
      h8 A0 = wp[(4 + mt) * 64 + lane];  // ks=0
      h8 A1 = wp[(8 + mt) * 64 + lane];  // ks=1
      f32x4 a[4];
#pragma unroll
      for (int nt = 0; nt < 4; ++nt) a[nt] = (f32x4){0.f, 0.f, 0.f, 0.f};
#pragma unroll
      for (int nt = 0; nt < 4; ++nt)
        a[nt] = __builtin_amdgcn_mfma_f32_16x16x32_f16(A0, B2[0][nt], a[nt], 0, 0, 0);
#pragma unroll
      for (int nt = 0; nt < 4; ++nt)
        a[nt] = __builtin_amdgcn_mfma_f32_16x16x32_f16(A1, B2[1][nt], a[nt], 0, 0, 0);
#pragma unroll
      for (int nt = 0; nt < 4; ++nt) {
        uint2 v = tanh4_pk(a[nt]);
        *(uint2*)&Wu[(16 * nt + r) * 18 + 8 * mtl + 2 * g] = v;
      }
    }
#pragma unroll
    for (int nt = 0; nt < 4; ++nt) {
      short4v lo = *(short4v*)&W[(16 * nt + r) * XSTR + 8 * g];
      short4v hi = *(short4v*)&W[(16 * nt + r) * XSTR + 8 * g + 4];
      short8 s = __builtin_shufflevector(lo, hi, 0, 1, 2, 3, 4, 5, 6, 7);
      B3[half][nt] = __builtin_bit_cast(h8, s);
    }
  }

  // ---- L3 (64->12): M=16 (12 valid), K=64 ----
  f32x4 acc3[4];
#pragma unroll
  for (int nt = 0; nt < 4; ++nt) acc3[nt] = (f32x4){0.f, 0.f, 0.f, 0.f};
  {
    h8 A0 = wp[12 * 64 + lane];
    h8 A1 = wp[13 * 64 + lane];
#pragma unroll
    for (int nt = 0; nt < 4; ++nt)
      acc3[nt] = __builtin_amdgcn_mfma_f32_16x16x32_f16(A0, B3[0][nt], acc3[nt], 0, 0, 0);
#pragma unroll
    for (int nt = 0; nt < 4; ++nt)
      acc3[nt] = __builtin_amdgcn_mfma_f32_16x16x32_f16(A1, B3[1][nt], acc3[nt], 0, 0, 0);
  }

  // ---- store: lane(g<3, r) holds channels 4g..4g+3 of pixel 16nt+r ----
  if (g < 3) {
#pragma unroll
    for (int nt = 0; nt < 4; ++nt) {
      int pix = pixbase + 16 * nt + r;
      *(f32x4*)(out + pix * 12 + 4 * g) = acc3[nt];
    }
  }
}

extern "C" void kernel_launch(void* const* d_in, const int* in_sizes, int n_in,
                              void* d_out, int out_size, void* d_ws, size_t ws_size,
                              hipStream_t stream) {
  const float* rgb = (const float*)d_in[0];
  const float* g0 = (const float*)d_in[1];
  const float* g1 = (const float*)d_in[2];
  const float* g2 = (const float*)d_in[3];
  const float* w1 = (const float*)d_in[4];
  const float* w2 = (const float*)d_in[5];
  const float* w3 = (const float*)d_in[6];
  const int* cam = (const int*)d_in[7];
  float* out = (float*)d_out;

  hipLaunchKernelGGL(prep_kernel, dim3(64), dim3(256), 0, stream,
                     g0, g1, g2, w1, w2, w3, cam, d_ws);
  hipLaunchKernelGGL(msnbat_kernel, dim3(NPIX / 64), dim3(64), 0, stream,
                     rgb, d_ws, out);
}

// Round 14
// 51.627 us; speedup vs baseline: 1.0988x; 1.0988x over previous
//
#include <hip/hip_runtime.h>
#include <hip/hip_bf16.h>

#define H_IMG 720
#define W_IMG 1280
#define NPIX (H_IMG * W_IMG)

typedef __attribute__((ext_vector_type(4))) float f32x4;
typedef __attribute__((ext_vector_type(8))) short short8;
typedef __attribute__((ext_vector_type(4))) short short4v;
typedef __attribute__((ext_vector_type(4))) uint u32x4;
typedef _Float16 h8 __attribute__((ext_vector_type(8)));

// ---- workspace layout (bytes) ----
// wpack: 14 f16 A-frags * 64 lanes * 16B
#define WPACK_BYTES (14 * 64 * 16)
#define GP0_OFF WPACK_BYTES                  // 14336 (16-aligned)
#define GP0_N (16 * 16 * 8 * 8)              // f16 elems, [y][x][z][c]
#define GP1_OFF (GP0_OFF + GP0_N * 2)        // 47104
#define GP1_N (12 * 12 * 8 * 8)
#define GP2_OFF (GP1_OFF + GP1_N * 2)        // 65536
#define GP2_N (8 * 8 * 4 * 8)

// Staging row: 64 f16 payload + 4 pad = 68 ushorts (34 uints, 136 B).
// 34 mod 32 = 2 -> 16 r-rows hit 16 distinct even bank starts (r4-r12's
// conflict-free generator property). Full 64-feat H row fits (r13's bug:
// 36-ushort rows overflowed at mt>=2).
#define HSTR 68

// 2*log2(e): folded into w1/w2 at prep so MFMA emits exp2-ready values.
#define KSCALE 2.885390081777927f

__device__ __forceinline__ uint pkh(float a, float b) {
  // v_cvt_pkrtz_f16_f32: 2 f32 -> packed f16x2, one instruction
  auto t = __builtin_amdgcn_cvt_pkrtz(a, b);  // __fp16 ext_vector(2)
  return __builtin_bit_cast(uint, t);
}

// tanh with pre-scaled input u = 2*log2(e)*x: 4 ops, independent per value.
__device__ __forceinline__ float tanhu(float u) {
  float e2 = __builtin_amdgcn_exp2f(u);
  float r = __builtin_amdgcn_rcpf(e2 + 1.f);
  return fmaf(-2.f, r, 1.f);
}

__device__ __forceinline__ uint2 tanh4(f32x4 u) {
  return make_uint2(pkh(tanhu(u[0]), tanhu(u[1])), pkh(tanhu(u[2]), tanhu(u[3])));
}

// ================= prep kernel =================
__global__ __launch_bounds__(256) void prep_kernel(
    const float* __restrict__ g0, const float* __restrict__ g1, const float* __restrict__ g2,
    const float* __restrict__ w1, const float* __restrict__ w2, const float* __restrict__ w3,
    const int* __restrict__ cam, void* __restrict__ ws) {
  ushort* wpack = (ushort*)ws;
  ushort* gp0 = (ushort*)((char*)ws + GP0_OFF);
  ushort* gp1 = (ushort*)((char*)ws + GP1_OFF);
  ushort* gp2 = (ushort*)((char*)ws + GP2_OFF);
  const int ci = cam[0];
  const int tid = blockIdx.x * 256 + threadIdx.x;
  const int nth = gridDim.x * 256;

  // grids -> [y][x][z][c] f16, selected view only
  for (int e = tid; e < GP0_N; e += nth) {
    int c = e & 7; int t = e >> 3; int z = t & 7; t >>= 3; int x = t & 15; int y = t >> 4;
    _Float16 hv = (_Float16)g0[ci * GP0_N + ((c * 8 + z) * 16 + y) * 16 + x];
    gp0[e] = __builtin_bit_cast(ushort, hv);
  }
  for (int e = tid; e < GP1_N; e += nth) {
    int c = e & 7; int t = e >> 3; int z = t & 7; t >>= 3; int x = t % 12; int y = t / 12;
    _Float16 hv = (_Float16)g1[ci * GP1_N + ((c * 8 + z) * 12 + y) * 12 + x];
    gp1[e] = __builtin_bit_cast(ushort, hv);
  }
  for (int e = tid; e < GP2_N; e += nth) {
    int c = e & 7; int t = e >> 3; int z = t & 3; t >>= 2; int x = t & 7; int y = t >> 3;
    _Float16 hv = (_Float16)g2[ci * GP2_N + ((c * 4 + z) * 8 + y) * 8 + x];
    gp2[e] = __builtin_bit_cast(ushort, hv);
  }

  // weights -> per-lane f16 A-fragments (A = W^T).
  // frag f: 0..3 = L1 (mt), 4..11 = L2 (4+ks*4+mt), 12..13 = L3 (ks).
  // w1/w2 are scaled by KSCALE (tanh exp2 pre-scale); w3 raw.
  for (int fl = tid; fl < 14 * 64; fl += nth) {
    int f = fl >> 6, lane = fl & 63;
    int g = lane >> 4, r = lane & 15;
    ushort* dh = wpack + fl * 8;
#pragma unroll
    for (int j = 0; j < 8; ++j) {
      float v = 0.f;
      if (f < 4) {
        int k = 8 * g + j, n = r + 16 * f;
        if (k < 24) v = w1[k * 64 + n] * KSCALE;
      } else if (f < 12) {
        int q = f - 4, ks = q >> 2, mt = q & 3;
        v = w2[(8 * g + j + 32 * ks) * 64 + (r + 16 * mt)] * KSCALE;
      } else {
        int ks = f - 12;
        if (r < 12) v = w3[(8 * g + j + 32 * ks) * 12 + r];
      }
      _Float16 hv = (_Float16)v;
      dh[j] = __builtin_bit_cast(ushort, hv);
    }
  }
}

// ================= slicing (packed f16) =================
template <int WG, int HG, int LG>
__device__ __forceinline__ h8 slice_h8(const h8* __restrict__ gp,
                                       int row, int col, float gray) {
  float x = (float)col * ((float)(WG - 1) / (float)(W_IMG - 1));
  float y = (float)row * ((float)(HG - 1) / (float)(H_IMG - 1));
  float z = gray * (float)(LG - 1);
  int x0 = (int)x, y0 = (int)y, z0 = (int)z;
  int x1 = min(x0 + 1, WG - 1), y1 = min(y0 + 1, HG - 1), z1 = min(z0 + 1, LG - 1);
  _Float16 wx = (_Float16)(x - (float)x0);
  _Float16 wy = (_Float16)(y - (float)y0);
  _Float16 wz = (_Float16)(z - (float)z0);
  h8 wx8 = {wx, wx, wx, wx, wx, wx, wx, wx};
  h8 wy8 = {wy, wy, wy, wy, wy, wy, wy, wy};
  h8 wz8 = {wz, wz, wz, wz, wz, wz, wz, wz};

  const h8* p00 = gp + (y0 * WG + x0) * LG;
  const h8* p01 = gp + (y0 * WG + x1) * LG;
  const h8* p10 = gp + (y1 * WG + x0) * LG;
  const h8* p11 = gp + (y1 * WG + x1) * LG;

  h8 a00 = p00[z0], a01 = p01[z0], a10 = p10[z0], a11 = p11[z0];
  h8 b00 = p00[z1], b01 = p01[z1], b10 = p10[z1], b11 = p11[z1];

  h8 xa = a00 + wx8 * (a01 - a00);
  h8 xb = a10 + wx8 * (a11 - a10);
  h8 ya = xa + wy8 * (xb - xa);
  h8 xc = b00 + wx8 * (b01 - b00);
  h8 xd = b10 + wx8 * (b11 - b10);
  h8 yb = xc + wy8 * (xd - xc);
  return ya + wz8 * (yb - ya);
}

// ================= main kernel =================
// 1-wave workgroups; wave-private LDS staging; no barriers. f16 end-to-end.
// Full-layer accumulate: one LDS write->read rendezvous per layer (r13 theory,
// with correctly sized 68-ushort rows). KSCALE folded into w1/w2; 4-op tanh.
// launch_bounds(64,4): VGPR budget 128; est. peak liveness ~115-125.
__global__ __launch_bounds__(64, 4) void msnbat_kernel(
    const float* __restrict__ rgb, const void* __restrict__ ws, float* __restrict__ out) {
  __shared__ ushort W[64 * HSTR];  // 8704 B/block
  uint* Wu = (uint*)W;

  const h8* wp = (const h8*)ws;  // A-frag f, lane l -> wp[f*64+l]
  const h8* gp0 = (const h8*)((const char*)ws + GP0_OFF);
  const h8* gp1 = (const h8*)((const char*)ws + GP1_OFF);
  const h8* gp2 = (const h8*)((const char*)ws + GP2_OFF);

  const int lane = threadIdx.x;
  const int g = lane >> 4, r = lane & 15;
  const int pixbase = blockIdx.x * 64;
  const int p = pixbase + lane;
  const int row = p / W_IMG;
  const int col = p - row * W_IMG;

  const float rr = rgb[p * 3 + 0], gg = rgb[p * 3 + 1], bb = rgb[p * 3 + 2];
  const float gray = fminf(fmaxf(rr * 0.299f + gg * 0.587f + bb * 0.114f, 0.f), 1.f);

  // ---- slice 24 features (lane = its own pixel), f16 vectors ----
  h8 f0 = slice_h8<16, 16, 8>(gp0, row, col, gray);
  h8 f1 = slice_h8<12, 12, 8>(gp1, row, col, gray);
  h8 f2 = slice_h8<8, 8, 4>(gp2, row, col, gray);

  // ---- stage X: row = pixel(lane), cols 0..23 f16 feats (24..31 unwritten) ----
  {
    const int ub = lane * (HSTR / 2);  // uint base of this row
    u32x4 u0 = __builtin_bit_cast(u32x4, f0);
    u32x4 u1 = __builtin_bit_cast(u32x4, f1);
    u32x4 u2 = __builtin_bit_cast(u32x4, f2);
    *(uint2*)&Wu[ub + 0] = make_uint2(u0[0], u0[1]);
    *(uint2*)&Wu[ub + 2] = make_uint2(u0[2], u0[3]);
    *(uint2*)&Wu[ub + 4] = make_uint2(u1[0], u1[1]);
    *(uint2*)&Wu[ub + 6] = make_uint2(u1[2], u1[3]);
    *(uint2*)&Wu[ub + 8] = make_uint2(u2[0], u2[1]);
    *(uint2*)&Wu[ub + 10] = make_uint2(u2[2], u2[3]);
  }

  const h8 zero8 = (h8){0, 0, 0, 0, 0, 0, 0, 0};

  // ---- B1 frags: lane(g,r) reads X[pixel r+16nt][feat 8g+j]; g==3 = K-pad -> 0 ----
  h8 B1[4];
#pragma unroll
  for (int nt = 0; nt < 4; ++nt) {
    short4v lo = *(short4v*)&W[(r + 16 * nt) * HSTR + 8 * g];
    short4v hi = *(short4v*)&W[(r + 16 * nt) * HSTR + 8 * g + 4];
    short8 s = __builtin_shufflevector(lo, hi, 0, 1, 2, 3, 4, 5, 6, 7);
    B1[nt] = (g < 3) ? __builtin_bit_cast(h8, s) : zero8;
  }

  // ---- L1 (24->64): all 16 MFMAs back-to-back, then tanh, one rendezvous ----
  {
    f32x4 a1[4][4];
#pragma unroll
    for (int mt = 0; mt < 4; ++mt)
#pragma unroll
      for (int nt = 0; nt < 4; ++nt) a1[mt][nt] = (f32x4){0.f, 0.f, 0.f, 0.f};
#pragma unroll
    for (int mt = 0; mt < 4; ++mt) {
      h8 A = wp[mt * 64 + lane];
#pragma unroll
      for (int nt = 0; nt < 4; ++nt)
        a1[mt][nt] = __builtin_amdgcn_mfma_f32_16x16x32_f16(A, B1[nt], a1[mt][nt], 0, 0, 0);
    }
    // tanh(H1) -> LDS: lane(g,r) writes feats 16mt+4g..+3 of pixel 16nt+r
#pragma unroll
    for (int mt = 0; mt < 4; ++mt)
#pragma unroll
      for (int nt = 0; nt < 4; ++nt)
        *(uint2*)&Wu[(16 * nt + r) * (HSTR / 2) + 8 * mt + 2 * g] = tanh4(a1[mt][nt]);
  }

  // ---- B2 frags: H1[pixel r+16nt][feat 8g+j+32ks] ----
  h8 B2[2][4];
#pragma unroll
  for (int ks = 0; ks < 2; ++ks)
#pragma unroll
    for (int nt = 0; nt < 4; ++nt) {
      short4v lo = *(short4v*)&W[(16 * nt + r) * HSTR + 32 * ks + 8 * g];
      short4v hi = *(short4v*)&W[(16 * nt + r) * HSTR + 32 * ks + 8 * g + 4];
      short8 s = __builtin_shufflevector(lo, hi, 0, 1, 2, 3, 4, 5, 6, 7);
      B2[ks][nt] = __builtin_bit_cast(h8, s);
    }

  // ---- L2 (64->64): all 32 MFMAs, then tanh, one rendezvous ----
  {
    f32x4 a2[4][4];
#pragma unroll
    for (int mt = 0; mt < 4; ++mt)
#pragma unroll
      for (int nt = 0; nt < 4; ++nt) a2[mt][nt] = (f32x4){0.f, 0.f, 0.f, 0.f};
#pragma unroll
    for (int ks = 0; ks < 2; ++ks)
#pragma unroll
      for (int mt = 0; mt < 4; ++mt) {
        h8 A = wp[(4 + ks * 4 + mt) * 64 + lane];
#pragma unroll
        for (int nt = 0; nt < 4; ++nt)
          a2[mt][nt] = __builtin_amdgcn_mfma_f32_16x16x32_f16(A, B2[ks][nt], a2[mt][nt], 0, 0, 0);
      }
#pragma unroll
    for (int mt = 0; mt < 4; ++mt)
#pragma unroll
      for (int nt = 0; nt < 4; ++nt)
        *(uint2*)&Wu[(16 * nt + r) * (HSTR / 2) + 8 * mt + 2 * g] = tanh4(a2[mt][nt]);
  }

  // ---- B3 frags + L3 (64->12): M=16 (12 valid), K=64 ----
  f32x4 acc3[4];
#pragma unroll
  for (int nt = 0; nt < 4; ++nt) acc3[nt] = (f32x4){0.f, 0.f, 0.f, 0.f};
#pragma unroll
  for (int ks = 0; ks < 2; ++ks) {
    h8 A = wp[(12 + ks) * 64 + lane];
#pragma unroll
    for (int nt = 0; nt < 4; ++nt) {
      short4v lo = *(short4v*)&W[(16 * nt + r) * HSTR + 32 * ks + 8 * g];
      short4v hi = *(short4v*)&W[(16 * nt + r) * HSTR + 32 * ks + 8 * g + 4];
      short8 s = __builtin_shufflevector(lo, hi, 0, 1, 2, 3, 4, 5, 6, 7);
      h8 B = __builtin_bit_cast(h8, s);
      acc3[nt] = __builtin_amdgcn_mfma_f32_16x16x32_f16(A, B, acc3[nt], 0, 0, 0);
    }
  }

  // ---- store: lane(g<3, r) holds channels 4g..4g+3 of pixel 16nt+r ----
  if (g < 3) {
#pragma unroll
    for (int nt = 0; nt < 4; ++nt) {
      int pix = pixbase + 16 * nt + r;
      *(f32x4*)(out + pix * 12 + 4 * g) = acc3[nt];
    }
  }
}

extern "C" void kernel_launch(void* const* d_in, const int* in_sizes, int n_in,
                              void* d_out, int out_size, void* d_ws, size_t ws_size,
                              hipStream_t stream) {
  const float* rgb = (const float*)d_in[0];
  const float* g0 = (const float*)d_in[1];
  const float* g1 = (const float*)d_in[2];
  const float* g2 = (const float*)d_in[3];
  const float* w1 = (const float*)d_in[4];
  const float* w2 = (const float*)d_in[5];
  const float* w3 = (const float*)d_in[6];
  const int* cam = (const int*)d_in[7];
  float* out = (float*)d_out;

  hipLaunchKernelGGL(prep_kernel, dim3(64), dim3(256), 0, stream,
                     g0, g1, g2, w1, w2, w3, cam, d_ws);
  hipLaunchKernelGGL(msnbat_kernel, dim3(NPIX / 64), dim3(64), 0, stream,
                     rgb, d_ws, out);
}